// Round 12
// baseline (730.907 us; speedup 1.0000x reference)
//
#include <hip/hip_runtime.h>

typedef __attribute__((ext_vector_type(8))) short short8;
typedef __attribute__((ext_vector_type(4))) short s4v;
typedef __attribute__((ext_vector_type(4))) float floatx4;

#define SPOS 16384
#define NT 4   // tiles of 32 positions per block

// round-to-nearest-even fp32 -> bf16 bits
__device__ __forceinline__ unsigned short f2bf(float f) {
    unsigned u = __float_as_uint(f);
    u += 0x7fffu + ((u >> 16) & 1u);
    return (unsigned short)(u >> 16);
}

// Branchless bit-twiddle posit quantizer (verified equivalent of the 128
// sequential where-passes).
__device__ __forceinline__ float posit_q(float x) {
    unsigned xu  = __float_as_uint(x);
    unsigned sgn = xu & 0x80000000u;
    unsigned au  = xu & 0x7fffffffu;
    unsigned m   = au & 0x007fffffu;
    unsigned r   = (au + 0x00080000u) & 0xfff00000u;
    bool bdry = (m & 0x000fffffu) == 0x00080000u;
    unsigned res;
    if (au >= 0x3f800000u) {                      // |x| >= 1
        res = r;
        if (m > 0x00700000u && m < 0x00780000u && au < 0x47700000u)
            res = (au & 0xff800000u) + 0x00800000u;   // -> 2^(E+1)
        if ((bdry && m != 0x00780000u) || au >= 0x47780000u)
            res = au;                              // boundaries & clamp unchanged
    } else {                                       // |x| < 1
        res = (m <= 0x00080000u || m >= 0x00780000u || bdry) ? au : r;
        if (au < 0x37880000u) res = au ? 0x37800000u : 0u;  // -> 2^-16 (0 stays 0)
    }
    return __uint_as_float(sgn | res);
}

// Same, for z >= 0 (post-ReLU) — sign handling dropped, bit-identical result.
__device__ __forceinline__ float posit_q_pos(float z) {
    unsigned au  = __float_as_uint(z);
    unsigned m   = au & 0x007fffffu;
    unsigned r   = (au + 0x00080000u) & 0xfff00000u;
    bool bdry = (m & 0x000fffffu) == 0x00080000u;
    unsigned res;
    if (au >= 0x3f800000u) {
        res = r;
        if (m > 0x00700000u && m < 0x00780000u && au < 0x47700000u)
            res = (au & 0xff800000u) + 0x00800000u;
        if ((bdry && m != 0x00780000u) || au >= 0x47780000u)
            res = au;
    } else {
        res = (m <= 0x00080000u || m >= 0x00780000u || bdry) ? au : r;
        if (au < 0x37880000u) res = au ? 0x37800000u : 0u;
    }
    return __uint_as_float(res);
}

// Quantize weights to bf16 in MFMA-FRAGMENT-PACKED order + fold BN constants.
// Packed layout: i = G*4096 + kb*512 + lane*8 + j  (G=row-group of 16, kb=K-block
// of 32, lane=wave lane, j=0..7) holds W[16G + (lane&15)][32kb + 8*(lane>>4) + j].
__global__ __launch_bounds__(256) void prep_kernel(
    const float* __restrict__ w1, const float* __restrict__ w2,
    const float* __restrict__ b1, const float* __restrict__ g1,
    const float* __restrict__ be1, const float* __restrict__ m1,
    const float* __restrict__ v1,
    const float* __restrict__ b2, const float* __restrict__ g2,
    const float* __restrict__ be2, const float* __restrict__ m2,
    const float* __restrict__ v2,
    unsigned short* __restrict__ w1p, unsigned short* __restrict__ w2p,
    float* __restrict__ cst)
{
    int i = blockIdx.x * 256 + threadIdx.x;
    if (i < 65536) {
        const int j    = i & 7;
        const int lane = (i >> 3) & 63;
        const int kb   = (i >> 9) & 7;
        const int G    = i >> 12;
        const int row  = 16 * G + (lane & 15);
        const int k    = 32 * kb + 8 * (lane >> 4) + j;
        w1p[i] = f2bf(posit_q(w1[row * 256 + k]));
        w2p[i] = f2bf(posit_q(w2[row * 256 + k]));
        if (i < 256) {
            float inv1 = g1[i] / sqrtf(v1[i] + 1e-5f);
            cst[i]       = inv1;
            cst[256 + i] = fmaf(b1[i], inv1, be1[i] - m1[i] * inv1);
            float inv2 = g2[i] / sqrtf(v2[i] + 1e-5f);
            cst[512 + i] = inv2;
            cst[768 + i] = fmaf(b2[i], inv2, be2[i] - m2[i] * inv2);
        }
    }
}

// q layout: 32 rows (p) x 32 column-blocks of 8 bf16, XOR-swizzled.
__device__ __forceinline__ int qidx(int p, int cb) {
    return p * 256 + ((cb ^ (p & 31)) << 3);
}

// R11: 4-TILE PIPELINED BLOCKS. Grid 1024 = exactly 4 blocks/CU (uniform
// residency, no tail). Per tile: quantize (with NEXT tile's x-loads issued
// into just-freed regs -> HBM latency hides under the tile's GEMMs), B1,
// GEMM1, epi1->q2, B2, GEMM2, epi2 (staged full-line stores via q1 scratch),
// B3 (protects q1 scratch vs next quantize). Weights L1/L2-hot on tiles 1-3.
__global__ __launch_bounds__(256, 4) void fused_kernel(
    const float* __restrict__ x,
    const unsigned short* __restrict__ w1p,
    const unsigned short* __restrict__ w2p,
    const float* __restrict__ cst,
    float* __restrict__ out)
{
    __shared__ alignas(16) unsigned short q1[32 * 256];  // 16 KB
    __shared__ alignas(16) unsigned short q2[32 * 256];  // 16 KB

    const int b  = blockIdx.x;          // 1024 blocks
    const int n  = b >> 7;              // image
    const int p0 = (b & 127) << 7;      // 128-position strip
    const float* xb = x   + (size_t)n * (256 * SPOS) + p0;
    float*       ob = out + (size_t)n * (256 * SPOS) + p0;

    const int t    = threadIdx.x;
    const int lane = t & 63;
    const int w    = t >> 6;            // wave id 0..3
    const int quad = lane >> 4;
    const int l15  = lane & 15;
    const int mbase = w * 64;

    // Phase-1 geometry (constant across tiles)
    const int g  = lane & 7;            // pos granule (4 pos)
    const int co = lane >> 3;           // 0..7 channel within block
    const int p5 = lane & 31, half = lane >> 5;
    const float* srcb = xb + (size_t)(64 * w + co) * SPOS + 4 * g;

    // Prologue: tile 0's x-loads
    floatx4 v[8];
    #pragma unroll
    for (int r = 0; r < 8; ++r)
        v[r] = *(const floatx4*)(srcb + (size_t)(8 * r) * SPOS);

    #pragma unroll 1
    for (int tt = 0; tt < NT; ++tt) {
        const int soff = 32 * tt;

        // ---- Phase 1: quantize tile tt -> q1; prefetch tile tt+1 into v.
        {
            float* xsw = (float*)q2 + w * 1024;   // wave-private strip (q2 dead)
            const float* srcn = srcb + soff + 32; // next tile
            #pragma unroll
            for (int dr = 0; dr < 4; ++dr) {
                // rows cl=co and cl=co+8; (co+8)&7 == co so same XOR key
                *(floatx4*)&xsw[co * 32 + 4 * (g ^ co)]       = v[2 * dr];
                *(floatx4*)&xsw[(co + 8) * 32 + 4 * (g ^ co)] = v[2 * dr + 1];
                if (tt + 1 < NT) {   // refill just-consumed regs from next tile
                    v[2 * dr]     = *(const floatx4*)(srcn + (size_t)(8 * (2 * dr)) * SPOS);
                    v[2 * dr + 1] = *(const floatx4*)(srcn + (size_t)(8 * (2 * dr + 1)) * SPOS);
                }
                short8 pk;
                #pragma unroll
                for (int j = 0; j < 8; ++j) {
                    const int cl = 8 * half + j;
                    const float val = xsw[cl * 32 + 4 * ((p5 >> 2) ^ (cl & 7)) + (p5 & 3)];
                    pk[j] = (short)f2bf(posit_q(val));
                }
                *(short8*)&q1[qidx(p5, 8 * w + 2 * dr + half)] = pk;
                // next dr overwrites strip: same-wave LDS ops in-order, safe
            }
        }
        __syncthreads();    // B1: q1 ready; q2 strip use finished

        floatx4 acc[4][2];
        #pragma unroll
        for (int i = 0; i < 4; ++i)
            #pragma unroll
            for (int jj = 0; jj < 2; ++jj)
                acc[i][jj] = (floatx4)0.0f;

        // ---- GEMM1: A = W1p (L1/L2-hot after tile 0), B = q1 ----
        #pragma unroll
        for (int kk = 0; kk < 8; ++kk) {
            short8 af[4], bf[2];
            #pragma unroll
            for (int i = 0; i < 4; ++i)
                af[i] = *(const short8*)&w1p[(((w * 4 + i) * 8 + kk) * 64 + lane) * 8];
            #pragma unroll
            for (int jj = 0; jj < 2; ++jj)
                bf[jj] = *(const short8*)&q1[qidx(16 * jj + l15, 4 * kk + quad)];
            #pragma unroll
            for (int i = 0; i < 4; ++i)
                #pragma unroll
                for (int jj = 0; jj < 2; ++jj)
                    acc[i][jj] = __builtin_amdgcn_mfma_f32_16x16x32_bf16(af[i], bf[jj], acc[i][jj], 0, 0, 0);
        }

        // Prefetch GEMM2's first af set (hides under epilogue-1 VALU).
        short8 af20[4];
        #pragma unroll
        for (int i = 0; i < 4; ++i)
            af20[i] = *(const short8*)&w2p[(((w * 4 + i) * 8 + 0) * 64 + lane) * 8];

        // ---- Epilogue 1 (no barrier: q2 free since B1; wave-exclusive cols)
        {
            const float* sc1 = cst;
            const float* bi1 = cst + 256;
            #pragma unroll
            for (int i = 0; i < 4; ++i) {
                const int m0 = mbase + 16 * i + quad * 4;
                float sc[4], bi[4];
                #pragma unroll
                for (int r = 0; r < 4; ++r) { sc[r] = sc1[m0 + r]; bi[r] = bi1[m0 + r]; }
                #pragma unroll
                for (int jj = 0; jj < 2; ++jj) {
                    const int p = 16 * jj + l15;
                    s4v h;
                    #pragma unroll
                    for (int r = 0; r < 4; ++r) {
                        float z = fmaf(acc[i][jj][r], sc[r], bi[r]);
                        z = fmaxf(z, 0.0f);
                        h[r] = (short)f2bf(posit_q_pos(z));
                    }
                    *(s4v*)&q2[qidx(p, m0 >> 3) + (m0 & 7)] = h;
                }
            }
        }
        __syncthreads();    // B2: q2 (z1) ready; every wave done with q1

        // ---- GEMM2 (operand-SWAPPED): lane holds
        // acc[i][jj][r] = out[ch = 64w+16i+l15][pos = 16jj + 4*quad + r]
        #pragma unroll
        for (int i = 0; i < 4; ++i)
            #pragma unroll
            for (int jj = 0; jj < 2; ++jj)
                acc[i][jj] = (floatx4)0.0f;

        #pragma unroll
        for (int kk = 0; kk < 8; ++kk) {
            short8 af[4], bf[2];
            #pragma unroll
            for (int i = 0; i < 4; ++i)
                af[i] = (kk == 0) ? af20[i]
                      : *(const short8*)&w2p[(((w * 4 + i) * 8 + kk) * 64 + lane) * 8];
            #pragma unroll
            for (int jj = 0; jj < 2; ++jj)
                bf[jj] = *(const short8*)&q2[qidx(16 * jj + l15, 4 * kk + quad)];
            #pragma unroll
            for (int i = 0; i < 4; ++i)
                #pragma unroll
                for (int jj = 0; jj < 2; ++jj)
                    acc[i][jj] = __builtin_amdgcn_mfma_f32_16x16x32_bf16(bf[jj], af[i], acc[i][jj], 0, 0, 0);
        }

        // ---- Epilogue 2 (R8 full-line scheme; q1 scratch free since B2)
        {
            const float* sc2 = cst + 512;
            const float* bi2 = cst + 768;
            float* stg = (float*)q1 + w * 1024;   // 4 KB per wave
            const int row_g = lane >> 3, ge = lane & 7;

            floatx4 res[2][4];
            #pragma unroll
            for (int h = 0; h < 2; ++h)
                #pragma unroll
                for (int k = 0; k < 4; ++k) {
                    const int ch = mbase + 32 * h + 8 * k + row_g;
                    res[h][k] = *(const floatx4*)(xb + (size_t)ch * SPOS + soff + 4 * ge);
                }

            #pragma unroll
            for (int h = 0; h < 2; ++h) {
                #pragma unroll
                for (int i2 = 0; i2 < 2; ++i2) {
                    const int chl = 16 * i2 + l15;
                    #pragma unroll
                    for (int jj = 0; jj < 2; ++jj)
                        *(floatx4*)&stg[chl * 32 + 4 * ((4 * jj + quad) ^ (chl & 7))] = acc[2 * h + i2][jj];
                }
                // same-wave LDS in-order: reads below see writes above
                #pragma unroll
                for (int k = 0; k < 4; ++k) {
                    const int chl = 8 * k + row_g;            // chl&7 == row_g
                    const int ch  = mbase + 32 * h + chl;
                    floatx4 vv = *(const floatx4*)&stg[chl * 32 + 4 * (ge ^ row_g)];
                    const float sc = sc2[ch];
                    const float bi = bi2[ch];
                    floatx4 o;
                    #pragma unroll
                    for (int r = 0; r < 4; ++r)
                        o[r] = fmaxf(fmaf(vv[r], sc, bi) + res[h][k][r], 0.0f);
                    *(floatx4*)(ob + (size_t)ch * SPOS + soff + 4 * ge) = o;
                }
            }
        }
        __syncthreads();    // B3: q1 scratch reads done before next quantize
    }
}

extern "C" void kernel_launch(void* const* d_in, const int* in_sizes, int n_in,
                              void* d_out, int out_size, void* d_ws, size_t ws_size,
                              hipStream_t stream) {
    const float* x   = (const float*)d_in[0];
    const float* w1  = (const float*)d_in[1];
    const float* b1  = (const float*)d_in[2];
    const float* g1  = (const float*)d_in[3];
    const float* be1 = (const float*)d_in[4];
    const float* m1  = (const float*)d_in[5];
    const float* v1  = (const float*)d_in[6];
    const float* w2  = (const float*)d_in[7];
    const float* b2  = (const float*)d_in[8];
    const float* g2  = (const float*)d_in[9];
    const float* be2 = (const float*)d_in[10];
    const float* m2  = (const float*)d_in[11];
    const float* v2  = (const float*)d_in[12];

    unsigned short* w1p = (unsigned short*)d_ws;
    unsigned short* w2p = w1p + 65536;
    float* cst = (float*)(w2p + 65536);   // scale1|bias1|scale2|bias2

    prep_kernel<<<256, 256, 0, stream>>>(w1, w2, b1, g1, be1, m1, v1,
                                         b2, g2, be2, m2, v2, w1p, w2p, cst);
    fused_kernel<<<1024, 256, 0, stream>>>(x, w1p, w2p, cst, (float*)d_out);
}